// Round 6
// baseline (219.416 us; speedup 1.0000x reference)
//
#include <hip/hip_runtime.h>

// B=4, C=256, N=4096 attention modulation.
// out[b,c,i] = newL[b,i]*src[b,c,i] + newB[b,i],
// newL[b,i] = sum_j softmax_j(E)*oldL[j], E = src_i . ref_j over C.
//
// fp16 MFMA 32x32x16 flash, static softmax shift, MFMA-fragment-tiled fp16
// operands (every global access 1KB-coalesced). R6: B-tiles staged through
// double-buffered LDS so the 4 waves/block share one global read (R5 was
// L1-BW-bound at ~56 B/cyc/CU re-reading the same tile per wave).

#define B_ 4
#define C_ 256
#define N_ 4096
#define LOG2E 1.44269504f
#define SHIFT2 86.5617f      // 60 * log2(e)
#define JSLICE 16
#define BN_ (B_ * N_)
#define NT_ 8                // j-tiles per block

typedef _Float16 half_t;
typedef _Float16 v8h  __attribute__((ext_vector_type(8)));
typedef float    v16f __attribute__((ext_vector_type(16)));

// ------------------------------------------------- transpose (both inputs)
// fp32 [B][C][N] -> fp16 fragment-tiled; src additionally scaled by log2(e).
// Layout: t16[b][tile=n/32][kb=c/16][lane][e], lane=((c>>3)&1)*32+(n&31), e=c&7.
__global__ void k_transpose(const float* __restrict__ src,
                            const float* __restrict__ ref,
                            half_t* __restrict__ s16, half_t* __restrict__ r16) {
    __shared__ float tile[64][65];
    int z  = blockIdx.z;
    int b  = z & 3;
    const float* in  = (z < B_) ? src : ref;
    half_t*      out = (z < B_) ? s16 : r16;
    float scale      = (z < B_) ? LOG2E : 1.0f;
    int c0 = blockIdx.y * 64;
    int n0 = blockIdx.x * 64;
    int tx = threadIdx.x & 15, ty = threadIdx.x >> 4;
#pragma unroll
    for (int q = 0; q < 4; q++) {
        int c = ty + q * 16;
        float4 v = *(const float4*)(in + ((size_t)b * C_ + c0 + c) * N_ + n0 + tx * 4);
        tile[c][tx * 4 + 0] = v.x;
        tile[c][tx * 4 + 1] = v.y;
        tile[c][tx * 4 + 2] = v.z;
        tile[c][tx * 4 + 3] = v.w;
    }
    __syncthreads();
    int r   = threadIdx.x & 31;
    int lhi = (threadIdx.x >> 5) & 1;
    int wv  = threadIdx.x >> 6;          // kb_local 0..3
#pragma unroll
    for (int nt = 0; nt < 2; nt++) {
        int nl = nt * 32 + r;
        v8h o;
#pragma unroll
        for (int e = 0; e < 8; e++)
            o[e] = (half_t)(tile[wv * 16 + lhi * 8 + e][nl] * scale);
        size_t tj = (size_t)(n0 >> 5) + nt;
        size_t kb = (size_t)(c0 >> 4) + wv;
        *(v8h*)(out + ((((size_t)b * 128 + tj) * 16 + kb) * 64 + (threadIdx.x & 63)) * 8) = o;
    }
}

// ----------------------------------------------------------- old lambda/beta
// grid (N/64, B), 256 thr: 64 n-columns x 4 c-quarters, LDS reduce.
__global__ void k_oldlb(const float* __restrict__ ref,
                        const float* __restrict__ wl, const float* __restrict__ bl,
                        const float* __restrict__ wb, const float* __restrict__ bb,
                        float* __restrict__ oldL, float* __restrict__ oldB) {
    int b  = blockIdx.y;
    int n0 = blockIdx.x * 64;
    int nl = threadIdx.x & 63;
    int cq = threadIdx.x >> 6;           // 0..3
    const float* p = ref + ((size_t)b * C_ + cq * 64) * N_ + n0 + nl;
    float aL = 0.f, aB = 0.f;
#pragma unroll 8
    for (int c = 0; c < 64; c++) {
        float v = p[(size_t)c * N_];
        aL += v * wl[cq * 64 + c];
        aB += v * wb[cq * 64 + c];
    }
    __shared__ float red[8][64];
    red[cq][nl]     = aL;
    red[4 + cq][nl] = aB;
    __syncthreads();
    if (threadIdx.x < 64) {
        int t = threadIdx.x;
        oldL[(size_t)b * N_ + n0 + t] =
            red[0][t] + red[1][t] + red[2][t] + red[3][t] + bl[0];
    } else if (threadIdx.x < 128) {
        int t = threadIdx.x - 64;
        oldB[(size_t)b * N_ + n0 + t] =
            red[4][t] + red[5][t] + red[6][t] + red[7][t] + bb[0];
    }
}

// ------------------------------------------------------------------ flash
// grid 2048 = B(4) x jslice(16) x itile(32):
//   b = bid&3 (XCD spread), jslice = (bid>>2)&15, itile = bid>>6.
// block = 256 thr = 4 waves; wave owns 32 i-rows; the 8 B-tiles (16KB each)
// are staged once per block through double-buffered LDS and shared by all
// 4 waves. Loads for tile jt+1 issue after the barrier, ds_writes happen
// after compute -> load latency hidden, barrier drains cheap.
__global__ __launch_bounds__(256, 3) void k_flash(
        const half_t* __restrict__ sT, const half_t* __restrict__ rT,
        const float* __restrict__ oldL, const float* __restrict__ oldB,
        float* __restrict__ part /* [JSLICE][3][B*N] */) {
    __shared__ half_t lds[2][8192];      // 2 x 16KB
    int bid    = blockIdx.x;
    int b      = bid & 3;
    int jslice = (bid >> 2) & (JSLICE - 1);
    int itile  = bid >> 6;
    int tid    = threadIdx.x;
    int wv     = tid >> 6;
    int lane   = tid & 63;
    int l31    = lane & 31, lhi = lane >> 5;
    int ti     = itile * 4 + wv;          // 32-row A tile index
    int i0     = ti * 32;
    int j0     = jslice * (N_ / JSLICE);  // 256 j per block
    int tj0    = j0 >> 5;

    // A fragments: one coalesced 1KB load per kb.
    const half_t* aP = sT + (((size_t)b * 128 + ti) * 16) * 512 + (size_t)lane * 8;
    v8h a[16];
#pragma unroll
    for (int kb = 0; kb < 16; kb++) a[kb] = *(const v8h*)(aP + (size_t)kb * 512);

    const half_t* bBase = rT + (((size_t)b * 128 + tj0) * 16) * 512;  // block-uniform
    const float*  oLp = oldL + (size_t)b * N_ + j0 + l31;
    const float*  oBp = oldB + (size_t)b * N_ + j0 + l31;

    float sp[16], sl[16], sb[16];
#pragma unroll
    for (int r = 0; r < 16; r++) { sp[r] = 0.f; sl[r] = 0.f; sb[r] = 0.f; }

    // Prologue: stage tile 0 into buffer 0.
    v8h st[4];
    {
        const v8h* g = (const v8h*)bBase;
        st[0] = g[tid]; st[1] = g[tid + 256]; st[2] = g[tid + 512]; st[3] = g[tid + 768];
        v8h* l = (v8h*)lds[0];
        l[tid] = st[0]; l[tid + 256] = st[1]; l[tid + 512] = st[2]; l[tid + 768] = st[3];
    }

    for (int jt = 0; jt < NT_; jt++) {
        __syncthreads();                       // buf[jt&1] fully written
        if (jt + 1 < NT_) {                    // issue next tile's loads early
            const v8h* g = (const v8h*)(bBase + (size_t)(jt + 1) * 8192);
            st[0] = g[tid]; st[1] = g[tid + 256]; st[2] = g[tid + 512]; st[3] = g[tid + 768];
        }
        const half_t* bt = lds[jt & 1] + (size_t)lane * 8;
        v16f acc;
#pragma unroll
        for (int r = 0; r < 16; r++) acc[r] = -SHIFT2;
#pragma unroll
        for (int kb = 0; kb < 16; kb++) {
            v8h bf = *(const v8h*)(bt + (size_t)kb * 512);
            acc = __builtin_amdgcn_mfma_f32_32x32x16_f16(a[kb], bf, acc, 0, 0, 0);
        }
        float lam = oLp[jt * 32], bet = oBp[jt * 32];
#pragma unroll
        for (int r = 0; r < 16; r++) {
            float p = __builtin_amdgcn_exp2f(acc[r]);
            sp[r] += p;
            sl[r] += p * lam;
            sb[r] += p * bet;
        }
        if (jt + 1 < NT_) {                    // write next buffer after compute
            v8h* l = (v8h*)lds[(jt + 1) & 1];
            l[tid] = st[0]; l[tid + 256] = st[1]; l[tid + 512] = st[2]; l[tid + 768] = st[3];
        }
    }

    float* pSP = part + ((size_t)jslice * 3 + 0) * BN_;
    float* pSL = part + ((size_t)jslice * 3 + 1) * BN_;
    float* pSB = part + ((size_t)jslice * 3 + 2) * BN_;
#pragma unroll
    for (int r = 0; r < 16; r++) {
        float tp = sp[r], tl = sl[r], tb = sb[r];
#pragma unroll
        for (int m = 1; m <= 16; m <<= 1) {
            tp += __shfl_xor(tp, m, 64);
            tl += __shfl_xor(tl, m, 64);
            tb += __shfl_xor(tb, m, 64);
        }
        if (l31 == 0) {
            // C/D layout: row = (reg&3) + 8*(reg>>2) + 4*(lane>>5)
            int row = (r & 3) + 8 * (r >> 2) + 4 * lhi;
            size_t ig = (size_t)b * N_ + i0 + row;
            pSP[ig] = tp; pSL[ig] = tl; pSB[ig] = tb;
        }
    }
}

// -------------------------------------------- reduce partials -> newL/newB
__global__ void k_reduce(const float* __restrict__ part,
                         float* __restrict__ newL, float* __restrict__ newB) {
    int bn = blockIdx.x * 256 + threadIdx.x;   // 0 .. B*N-1
    float sp = 0.f, sl = 0.f, sb = 0.f;
#pragma unroll
    for (int s = 0; s < JSLICE; s++) {
        sp += part[((size_t)s * 3 + 0) * BN_ + bn];
        sl += part[((size_t)s * 3 + 1) * BN_ + bn];
        sb += part[((size_t)s * 3 + 2) * BN_ + bn];
    }
    float inv = 1.0f / sp;
    newL[bn] = sl * inv;
    newB[bn] = sb * inv;
}

// --------------------------------------------------------------- modulation
__global__ void k_modulate(const float* __restrict__ src,
                           const float* __restrict__ newL,
                           const float* __restrict__ newB,
                           float* __restrict__ out) {
    size_t idx = ((size_t)blockIdx.x * 256 + threadIdx.x) * 4;
    int b = (int)(idx >> 20);                 // C_*N_ = 1<<20
    int n = (int)(idx & (size_t)(N_ - 1));
    size_t bn = (size_t)b * N_ + n;
    float4 L = *(const float4*)(newL + bn);
    float4 T = *(const float4*)(newB + bn);
    float4 s = *(const float4*)(src + idx);
    float4 o;
    o.x = L.x * s.x + T.x;
    o.y = L.y * s.y + T.y;
    o.z = L.z * s.z + T.z;
    o.w = L.w * s.w + T.w;
    *(float4*)(out + idx) = o;
}

extern "C" void kernel_launch(void* const* d_in, const int* in_sizes, int n_in,
                              void* d_out, int out_size, void* d_ws, size_t ws_size,
                              hipStream_t stream) {
    const float* src = (const float*)d_in[0];
    const float* ref = (const float*)d_in[1];
    const float* wl  = (const float*)d_in[2];
    const float* bl  = (const float*)d_in[3];
    const float* wb  = (const float*)d_in[4];
    const float* bb  = (const float*)d_in[5];
    float* out = (float*)d_out;

    float* oldL = (float*)d_ws;
    float* oldB = oldL + BN_;
    float* newL = oldB + BN_;
    float* newB = newL + BN_;
    float* part = newB + BN_;
    size_t needF  = ((size_t)4 + 3 * JSLICE) * BN_ * sizeof(float);
    size_t need16 = (size_t)2 * B_ * N_ * C_ * sizeof(half_t);
    half_t* s16;
    if (ws_size >= needF + need16) s16 = (half_t*)((char*)d_ws + needF);
    else                           s16 = (half_t*)d_out;   // overwritten by k_modulate
    half_t* r16 = s16 + (size_t)B_ * N_ * C_;

    k_transpose<<<dim3(N_ / 64, C_ / 64, 2 * B_), 256, 0, stream>>>(src, ref, s16, r16);
    k_oldlb<<<dim3(N_ / 64, B_), 256, 0, stream>>>(ref, wl, bl, wb, bb, oldL, oldB);
    k_flash<<<2048, 256, 0, stream>>>(s16, r16, oldL, oldB, part);
    k_reduce<<<BN_ / 256, 256, 0, stream>>>(part, newL, newB);
    k_modulate<<<(B_ * C_ * N_) / (256 * 4), 256, 0, stream>>>(src, newL, newB, out);
}

// Round 7
// 149.778 us; speedup vs baseline: 1.4649x; 1.4649x over previous
//
#include <hip/hip_runtime.h>

// B=4, C=256, N=4096 attention modulation.
// out[b,c,i] = newL[b,i]*src[b,c,i] + newB[b,i],
// newL[b,i] = sum_j softmax_j(E)*oldL[j], E = src_i . ref_j over C.
//
// fp16 MFMA 32x32x16 flash, static softmax shift, MFMA-fragment-tiled fp16
// operands. R7: B-tiles staged via __builtin_amdgcn_global_load_lds (16B,
// direct global->LDS DMA, double-buffered) -- R6's register-staged version
// spilled (FETCH 155MB / WRITE 244MB of scratch traffic). launch_bounds
// (256,2) so the ~140-VGPR working set can never spill.

#define B_ 4
#define C_ 256
#define N_ 4096
#define LOG2E 1.44269504f
#define SHIFT2 86.5617f      // 60 * log2(e)
#define JSLICE 16
#define BN_ (B_ * N_)
#define NT_ 8                // j-tiles per block

typedef _Float16 half_t;
typedef _Float16 v8h  __attribute__((ext_vector_type(8)));
typedef float    v16f __attribute__((ext_vector_type(16)));

#define GLDS16(g, l) __builtin_amdgcn_global_load_lds(                         \
    (const __attribute__((address_space(1))) void*)(g),                        \
    (__attribute__((address_space(3))) void*)(l), 16, 0, 0)

// --------------------------------------------- prep: transpose + old lambda
// z in [0,8): fp32 [B][C][N] -> fp16 fragment-tiled
//   t16[b][tile=n/32][kb=c/16][lane][e], lane=((c>>3)&1)*32+(n&31), e=c&7;
//   src (z<4) additionally scaled by log2(e).
// z == 8: oldL/oldB = 1x1 conv on ref (b = blockIdx.y, n0 = blockIdx.x*64).
__global__ void k_prep(const float* __restrict__ src,
                       const float* __restrict__ ref,
                       const float* __restrict__ wl, const float* __restrict__ bl,
                       const float* __restrict__ wb, const float* __restrict__ bb,
                       half_t* __restrict__ s16, half_t* __restrict__ r16,
                       float* __restrict__ oldL, float* __restrict__ oldB) {
    if (blockIdx.z == 8) {
        int b  = blockIdx.y;
        int n0 = blockIdx.x * 64;
        int nl = threadIdx.x & 63;
        int cq = threadIdx.x >> 6;           // 0..3
        const float* p = ref + ((size_t)b * C_ + cq * 64) * N_ + n0 + nl;
        float aL = 0.f, aB = 0.f;
#pragma unroll 8
        for (int c = 0; c < 64; c++) {
            float v = p[(size_t)c * N_];
            aL += v * wl[cq * 64 + c];
            aB += v * wb[cq * 64 + c];
        }
        __shared__ float red[8][64];
        red[cq][nl]     = aL;
        red[4 + cq][nl] = aB;
        __syncthreads();
        if (threadIdx.x < 64) {
            int t = threadIdx.x;
            oldL[(size_t)b * N_ + n0 + t] =
                red[0][t] + red[1][t] + red[2][t] + red[3][t] + bl[0];
        } else if (threadIdx.x < 128) {
            int t = threadIdx.x - 64;
            oldB[(size_t)b * N_ + n0 + t] =
                red[4][t] + red[5][t] + red[6][t] + red[7][t] + bb[0];
        }
        return;
    }
    __shared__ float tile[64][65];
    int z  = blockIdx.z;
    int b  = z & 3;
    const float* in  = (z < B_) ? src : ref;
    half_t*      out = (z < B_) ? s16 : r16;
    float scale      = (z < B_) ? LOG2E : 1.0f;
    int c0 = blockIdx.y * 64;
    int n0 = blockIdx.x * 64;
    int tx = threadIdx.x & 15, ty = threadIdx.x >> 4;
#pragma unroll
    for (int q = 0; q < 4; q++) {
        int c = ty + q * 16;
        float4 v = *(const float4*)(in + ((size_t)b * C_ + c0 + c) * N_ + n0 + tx * 4);
        tile[c][tx * 4 + 0] = v.x;
        tile[c][tx * 4 + 1] = v.y;
        tile[c][tx * 4 + 2] = v.z;
        tile[c][tx * 4 + 3] = v.w;
    }
    __syncthreads();
    int r   = threadIdx.x & 31;
    int lhi = (threadIdx.x >> 5) & 1;
    int wv  = threadIdx.x >> 6;          // kb_local 0..3
#pragma unroll
    for (int nt = 0; nt < 2; nt++) {
        int nl = nt * 32 + r;
        v8h o;
#pragma unroll
        for (int e = 0; e < 8; e++)
            o[e] = (half_t)(tile[wv * 16 + lhi * 8 + e][nl] * scale);
        size_t tj = (size_t)(n0 >> 5) + nt;
        size_t kb = (size_t)(c0 >> 4) + wv;
        *(v8h*)(out + ((((size_t)b * 128 + tj) * 16 + kb) * 64 + (threadIdx.x & 63)) * 8) = o;
    }
}

// ------------------------------------------------------------------ flash
// grid 2048 = B(4) x jslice(16) x itile(32):
//   b = bid&3 (XCD spread), jslice = (bid>>2)&15, itile = bid>>6.
// block = 256 thr = 4 waves; wave owns 32 i-rows; the 8 B-tiles (16KB) are
// staged once per block via global_load_lds (dwordx4) into double-buffered
// LDS and shared by all 4 waves. Prefetch for jt+1 issues right after the
// barrier; the next barrier's vmcnt drain guarantees completion.
__global__ __launch_bounds__(256, 2) void k_flash(
        const half_t* __restrict__ sT, const half_t* __restrict__ rT,
        const float* __restrict__ oldL, const float* __restrict__ oldB,
        float* __restrict__ part /* [JSLICE][3][B*N] */) {
    __shared__ half_t lds[2][8192];      // 2 x 16KB
    int bid    = blockIdx.x;
    int b      = bid & 3;
    int jslice = (bid >> 2) & (JSLICE - 1);
    int itile  = bid >> 6;
    int tid    = threadIdx.x;
    int wv     = tid >> 6;
    int lane   = tid & 63;
    int l31    = lane & 31, lhi = lane >> 5;
    int ti     = itile * 4 + wv;          // 32-row A tile index
    int i0     = ti * 32;
    int j0     = jslice * (N_ / JSLICE);  // 256 j per block
    int tj0    = j0 >> 5;

    // A fragments: one coalesced 1KB load per kb, held in VGPRs all kernel.
    const half_t* aP = sT + (((size_t)b * 128 + ti) * 16) * 512 + (size_t)lane * 8;
    v8h a[16];
#pragma unroll
    for (int kb = 0; kb < 16; kb++) a[kb] = *(const v8h*)(aP + (size_t)kb * 512);

    const half_t* bBase = rT + (((size_t)b * 128 + tj0) * 16) * 512;  // block-uniform
    const float*  oLp = oldL + (size_t)b * N_ + j0 + l31;
    const float*  oBp = oldB + (size_t)b * N_ + j0 + l31;

    float sp[16], sl[16], sb[16];
#pragma unroll
    for (int r = 0; r < 16; r++) { sp[r] = 0.f; sl[r] = 0.f; sb[r] = 0.f; }

    // Prologue: DMA tile 0 into buffer 0. Wave wv covers chunks (q*4+wv)*1KB.
#pragma unroll
    for (int q = 0; q < 4; q++) {
        int chunk = q * 4 + wv;
        GLDS16(bBase + (size_t)chunk * 512 + (size_t)lane * 8,
               &lds[0][(size_t)chunk * 512]);
    }

    for (int jt = 0; jt < NT_; jt++) {
        __syncthreads();                       // drains DMA -> buf[jt&1] ready
        if (jt + 1 < NT_) {                    // DMA next tile into other buffer
            const half_t* g = bBase + (size_t)(jt + 1) * 8192;
#pragma unroll
            for (int q = 0; q < 4; q++) {
                int chunk = q * 4 + wv;
                GLDS16(g + (size_t)chunk * 512 + (size_t)lane * 8,
                       &lds[(jt + 1) & 1][(size_t)chunk * 512]);
            }
        }
        const half_t* bt = lds[jt & 1] + (size_t)lane * 8;
        v16f acc;
#pragma unroll
        for (int r = 0; r < 16; r++) acc[r] = -SHIFT2;
#pragma unroll
        for (int kb = 0; kb < 16; kb++) {
            v8h bf = *(const v8h*)(bt + (size_t)kb * 512);
            acc = __builtin_amdgcn_mfma_f32_32x32x16_f16(a[kb], bf, acc, 0, 0, 0);
        }
        float lam = oLp[jt * 32], bet = oBp[jt * 32];
#pragma unroll
        for (int r = 0; r < 16; r++) {
            float p = __builtin_amdgcn_exp2f(acc[r]);
            sp[r] += p;
            sl[r] += p * lam;
            sb[r] += p * bet;
        }
    }

    float* pSP = part + ((size_t)jslice * 3 + 0) * BN_;
    float* pSL = part + ((size_t)jslice * 3 + 1) * BN_;
    float* pSB = part + ((size_t)jslice * 3 + 2) * BN_;
#pragma unroll
    for (int r = 0; r < 16; r++) {
        float tp = sp[r], tl = sl[r], tb = sb[r];
#pragma unroll
        for (int m = 1; m <= 16; m <<= 1) {
            tp += __shfl_xor(tp, m, 64);
            tl += __shfl_xor(tl, m, 64);
            tb += __shfl_xor(tb, m, 64);
        }
        if (l31 == 0) {
            // C/D layout: row = (reg&3) + 8*(reg>>2) + 4*(lane>>5)
            int row = (r & 3) + 8 * (r >> 2) + 4 * lhi;
            size_t ig = (size_t)b * N_ + i0 + row;
            pSP[ig] = tp; pSL[ig] = tl; pSB[ig] = tb;
        }
    }
}

// -------------------------------------------- reduce partials -> newL/newB
__global__ void k_reduce(const float* __restrict__ part,
                         float* __restrict__ newL, float* __restrict__ newB) {
    int bn = blockIdx.x * 256 + threadIdx.x;   // 0 .. B*N-1
    float sp = 0.f, sl = 0.f, sb = 0.f;
#pragma unroll
    for (int s = 0; s < JSLICE; s++) {
        sp += part[((size_t)s * 3 + 0) * BN_ + bn];
        sl += part[((size_t)s * 3 + 1) * BN_ + bn];
        sb += part[((size_t)s * 3 + 2) * BN_ + bn];
    }
    float inv = 1.0f / sp;
    newL[bn] = sl * inv;
    newB[bn] = sb * inv;
}

// --------------------------------------------------------------- modulation
__global__ void k_modulate(const float* __restrict__ src,
                           const float* __restrict__ newL,
                           const float* __restrict__ newB,
                           float* __restrict__ out) {
    size_t idx = ((size_t)blockIdx.x * 256 + threadIdx.x) * 4;
    int b = (int)(idx >> 20);                 // C_*N_ = 1<<20
    int n = (int)(idx & (size_t)(N_ - 1));
    size_t bn = (size_t)b * N_ + n;
    float4 L = *(const float4*)(newL + bn);
    float4 T = *(const float4*)(newB + bn);
    float4 s = *(const float4*)(src + idx);
    float4 o;
    o.x = L.x * s.x + T.x;
    o.y = L.y * s.y + T.y;
    o.z = L.z * s.z + T.z;
    o.w = L.w * s.w + T.w;
    *(float4*)(out + idx) = o;
}

extern "C" void kernel_launch(void* const* d_in, const int* in_sizes, int n_in,
                              void* d_out, int out_size, void* d_ws, size_t ws_size,
                              hipStream_t stream) {
    const float* src = (const float*)d_in[0];
    const float* ref = (const float*)d_in[1];
    const float* wl  = (const float*)d_in[2];
    const float* bl  = (const float*)d_in[3];
    const float* wb  = (const float*)d_in[4];
    const float* bb  = (const float*)d_in[5];
    float* out = (float*)d_out;

    float* oldL = (float*)d_ws;
    float* oldB = oldL + BN_;
    float* newL = oldB + BN_;
    float* newB = newL + BN_;
    float* part = newB + BN_;
    size_t needF  = ((size_t)4 + 3 * JSLICE) * BN_ * sizeof(float);
    size_t need16 = (size_t)2 * B_ * N_ * C_ * sizeof(half_t);
    half_t* s16;
    if (ws_size >= needF + need16) s16 = (half_t*)((char*)d_ws + needF);
    else                           s16 = (half_t*)d_out;   // overwritten by k_modulate
    half_t* r16 = s16 + (size_t)B_ * N_ * C_;

    k_prep<<<dim3(N_ / 64, C_ / 64, 9), 256, 0, stream>>>(
        src, ref, wl, bl, wb, bb, s16, r16, oldL, oldB);
    k_flash<<<2048, 256, 0, stream>>>(s16, r16, oldL, oldB, part);
    k_reduce<<<BN_ / 256, 256, 0, stream>>>(part, newL, newB);
    k_modulate<<<(B_ * C_ * N_) / (256 * 4), 256, 0, stream>>>(src, newL, newB, out);
}